// Round 2
// baseline (993.045 us; speedup 1.0000x reference)
//
#include <hip/hip_runtime.h>
#include <cfloat>

// VQ forward, MI355X. z[16,256,32,32] f32, emb[8192,256] f32, proj[256,256] f32.
// N = 16384 rows, K = 8192 codes, D = 256.
// d_out (floats): out[4194304] | loss | commitment | codebook_loss | idx_as_float[16384]
// d_ws: cbT[256][8192] | cb[8192][256] | norms[8192] | packed_u64[16384] | ssum | znorm[16384]
//
// Correctness-critical: the reference rounds d = (||z||^2 + ||e||^2) - 2*dot in fp32,
// quantizing scores to ulp(~256) ~ 1.5e-5 and creating index ties resolved by
// np.argmin's first-index rule. We emulate that rounding exactly (see fold in k_argmin).

constexpr int Dd = 256;
constexpr int Kc = 8192;
constexpr float INV_M = 1.0f / 4194304.0f;

__device__ __forceinline__ unsigned monof(float f) {
  unsigned u = __float_as_uint(f);
  return (u & 0x80000000u) ? ~u : (u | 0x80000000u);
}

// ---- K1: codebook = emb @ proj^T, written as cb[k][d] and cbT[d][k] ----
__global__ __launch_bounds__(256)
void k_codebook(const float* __restrict__ emb, const float* __restrict__ proj,
                float* __restrict__ cb, float* __restrict__ cbT) {
  __shared__ float et[64 * 65];
  __shared__ float pt[64 * 65];
  const int t = threadIdx.x;
  const int tx = t & 15, ty = t >> 4;
  const int kb = blockIdx.x * 64;
  const int db = blockIdx.y * 64;
  float acc[4][4];
#pragma unroll
  for (int u = 0; u < 4; ++u)
#pragma unroll
    for (int v = 0; v < 4; ++v) acc[u][v] = 0.f;

  const int jm = t & 15;
  const int q  = t >> 4;

  for (int jc = 0; jc < Dd; jc += 64) {
    __syncthreads();
#pragma unroll
    for (int i = 0; i < 4; ++i) {
      const int row = q + i * 16;
      const float4 e4 = *(const float4*)(emb  + (size_t)(kb + row) * Dd + jc + jm * 4);
      const float4 p4 = *(const float4*)(proj + (size_t)(db + row) * Dd + jc + jm * 4);
      et[(jm*4 + 0) * 65 + row] = e4.x;
      et[(jm*4 + 1) * 65 + row] = e4.y;
      et[(jm*4 + 2) * 65 + row] = e4.z;
      et[(jm*4 + 3) * 65 + row] = e4.w;
      pt[(jm*4 + 0) * 65 + row] = p4.x;
      pt[(jm*4 + 1) * 65 + row] = p4.y;
      pt[(jm*4 + 2) * 65 + row] = p4.z;
      pt[(jm*4 + 3) * 65 + row] = p4.w;
    }
    __syncthreads();
#pragma unroll 16
    for (int j = 0; j < 64; ++j) {
      float a[4], b[4];
#pragma unroll
      for (int u = 0; u < 4; ++u) a[u] = et[j*65 + ty*4 + u];
#pragma unroll
      for (int v = 0; v < 4; ++v) b[v] = pt[j*65 + tx*4 + v];
#pragma unroll
      for (int u = 0; u < 4; ++u)
#pragma unroll
        for (int v = 0; v < 4; ++v) acc[u][v] = fmaf(a[u], b[v], acc[u][v]);
    }
  }
#pragma unroll
  for (int u = 0; u < 4; ++u) {
    const int k = kb + ty*4 + u;
#pragma unroll
    for (int v = 0; v < 4; ++v) {
      const int d = db + tx*4 + v;
      cb [(size_t)k * Dd + d] = acc[u][v];
      cbT[(size_t)d * Kc + k] = acc[u][v];
    }
  }
}

// ---- K1b: per-code squared norms ----
__global__ __launch_bounds__(256)
void k_norms(const float* __restrict__ cbT, float* __restrict__ norms) {
  const int k = blockIdx.x * 256 + threadIdx.x;
  float s = 0.f;
  for (int d = 0; d < Dd; ++d) {
    const float v = cbT[(size_t)d * Kc + k];
    s = fmaf(v, v, s);
  }
  norms[k] = s;
}

// ---- K1c: per-row ||z||^2, computed ONCE so all k_argmin blocks see identical bits ----
__global__ __launch_bounds__(256)
void k_znorm(const float* __restrict__ z, float* __restrict__ znorm) {
  const int n = blockIdx.x * 256 + threadIdx.x;   // 16384 rows
  const float* p = z + (size_t)(n >> 10) * 262144 + (n & 1023);
  float s = 0.f;
  for (int d = 0; d < Dd; ++d) {
    const float v = p[(size_t)d * 1024];
    s = fmaf(v, v, s);
  }
  znorm[n] = s;
}

// ---- K2: fused distance + argmin.  128 n-rows x 1024 codes per block ----
// Emulates numpy fp32 rounding: Dq = fl( fl(znorm + enorm) - 2*dot ).
// 2*dot is exact (power of 2), so fl(t1 - 2*acc) is a single rounding.
__global__ __launch_bounds__(256)
void k_argmin(const float* __restrict__ z, const float* __restrict__ cbT,
              const float* __restrict__ norms, const float* __restrict__ znorm,
              unsigned long long* __restrict__ packed) {
  __shared__ float zs[32 * 128];
  __shared__ float es[32 * 128];
  const int t = threadIdx.x;
  const int tx = t & 15, ty = t >> 4;
  const int nbase = blockIdx.y * 128;
  const int kbase = blockIdx.x * 1024;
  const float* zb = z + (size_t)(nbase >> 10) * 262144 + (nbase & 1023);

  float zn[8];
#pragma unroll
  for (int r = 0; r < 8; ++r) zn[r] = znorm[nbase + ty * 8 + r];

  float mv[8];
  int   mi[8];
#pragma unroll
  for (int r = 0; r < 8; ++r) { mv[r] = FLT_MAX; mi[r] = 0; }

  const int sj = t >> 3;
  const int sm = t & 7;

  for (int kt = 0; kt < 8; ++kt) {
    const int kstart = kbase + kt * 128;
    float acc[8][8];
#pragma unroll
    for (int a = 0; a < 8; ++a)
#pragma unroll
      for (int b = 0; b < 8; ++b) acc[a][b] = 0.f;

    for (int dc = 0; dc < Dd; dc += 32) {
      __syncthreads();
      const float* gz = zb  + (size_t)(dc + sj) * 1024;
      const float* ge = cbT + (size_t)(dc + sj) * Kc + kstart;
#pragma unroll
      for (int i = 0; i < 4; ++i) {
        const int r0 = sm * 16 + i * 4;
        *(float4*)(zs + sj * 128 + r0) = *(const float4*)(gz + r0);
        *(float4*)(es + sj * 128 + r0) = *(const float4*)(ge + r0);
      }
      __syncthreads();
#pragma unroll 8
      for (int j = 0; j < 32; ++j) {
        const float4 a0 = *(const float4*)(zs + j*128 + ty*8);
        const float4 a1 = *(const float4*)(zs + j*128 + ty*8 + 4);
        const float4 b0 = *(const float4*)(es + j*128 + tx*8);
        const float4 b1 = *(const float4*)(es + j*128 + tx*8 + 4);
        const float zr[8] = {a0.x,a0.y,a0.z,a0.w,a1.x,a1.y,a1.z,a1.w};
        const float er[8] = {b0.x,b0.y,b0.z,b0.w,b1.x,b1.y,b1.z,b1.w};
#pragma unroll
        for (int rr = 0; rr < 8; ++rr)
#pragma unroll
          for (int cc = 0; cc < 8; ++cc)
            acc[rr][cc] = fmaf(zr[rr], er[cc], acc[rr][cc]);
      }
    }
    // Quantized fold (k ascending; strict '<' keeps earliest index).
#pragma unroll
    for (int cc = 0; cc < 8; ++cc) {
      const int k = kstart + tx * 8 + cc;
      const float nk = norms[k];
#pragma unroll
      for (int rr = 0; rr < 8; ++rr) {
        const float t1 = zn[rr] + nk;            // fp32, matches np elementwise add
        const float s  = t1 - 2.0f * acc[rr][cc]; // single fp32 rounding (2*acc exact)
        if (s < mv[rr]) { mv[rr] = s; mi[rr] = k; }
      }
    }
  }
  // (monof(s)<<32)|k : lexicographic (s,k) min => global first-index tie-break.
#pragma unroll
  for (int rr = 0; rr < 8; ++rr) {
    unsigned long long p =
        ((unsigned long long)monof(mv[rr]) << 32) | (unsigned)mi[rr];
#pragma unroll
    for (int m = 1; m < 16; m <<= 1) {
      const unsigned long long o = __shfl_xor(p, m, 64);
      if (o < p) p = o;
    }
    if (tx == 0) atomicMin(&packed[nbase + ty * 8 + rr], p);
  }
}

// ---- K3: gather codes, write out (NCHW), idx floats, reduce SSE ----
__global__ __launch_bounds__(256)
void k_output(const float* __restrict__ z, const float* __restrict__ cb,
              const unsigned long long* __restrict__ packed,
              float* __restrict__ out, float* __restrict__ idxf,
              float* __restrict__ ssum) {
  __shared__ float zqT[256 * 33];
  __shared__ float part[4];
  const int t = threadIdx.x;
  const int blk = blockIdx.x;       // = b*32 + h
  const int nbase = blk * 32;

  {
    const int nl = t >> 3, m = t & 7;
    const int idx = (int)(packed[nbase + nl] & 0xFFFFFFFFull);
    const float* row = cb + (size_t)idx * Dd;
#pragma unroll
    for (int i = 0; i < 8; ++i) {
      const int d0 = m * 4 + i * 32;
      const float4 v = *(const float4*)(row + d0);
      zqT[(d0 + 0) * 33 + nl] = v.x;
      zqT[(d0 + 1) * 33 + nl] = v.y;
      zqT[(d0 + 2) * 33 + nl] = v.z;
      zqT[(d0 + 3) * 33 + nl] = v.w;
    }
    if (t < 32)
      idxf[nbase + t] = (float)(unsigned)(packed[nbase + t] & 0xFFFFFFFFull);
  }
  __syncthreads();

  const int w = t & 31, cg = t >> 5;
  const size_t base = (size_t)(blk >> 5) * 262144 + (size_t)(blk & 31) * 32 + w;
  float local = 0.f;
#pragma unroll
  for (int cc = 0; cc < 32; ++cc) {
    const int c = cg * 32 + cc;
    const float q  = zqT[c * 33 + w];
    const float zv = z[base + (size_t)c * 1024];
    out[base + (size_t)c * 1024] = q;
    const float dd = q - zv;
    local = fmaf(dd, dd, local);
  }
  float v = local;
#pragma unroll
  for (int m = 1; m < 64; m <<= 1) v += __shfl_xor(v, m, 64);
  if ((t & 63) == 0) part[t >> 6] = v;
  __syncthreads();
  if (t == 0) atomicAdd(ssum, part[0] + part[1] + part[2] + part[3]);
}

// ---- K4: finalize scalars ----
__global__ void k_final(const float* __restrict__ ssum, float* __restrict__ scal) {
  const float m = *ssum * INV_M;
  scal[0] = 1.25f * m;   // loss
  scal[1] = 0.25f * m;   // commitment_loss
  scal[2] = m;           // codebook_loss
}

extern "C" void kernel_launch(void* const* d_in, const int* in_sizes, int n_in,
                              void* d_out, int out_size, void* d_ws, size_t ws_size,
                              hipStream_t stream) {
  const float* z    = (const float*)d_in[0];
  const float* emb  = (const float*)d_in[1];
  const float* proj = (const float*)d_in[2];

  float* out  = (float*)d_out;
  float* scal = out + 4194304;
  float* idxf = out + 4194307;

  float* cbT   = (float*)d_ws;                 // 8 MB
  float* cb    = cbT + 2097152;                // 8 MB
  float* norms = cb + 2097152;                 // 32 KB
  unsigned long long* packed =
      (unsigned long long*)(norms + 8192);     // 128 KB
  float* ssum  = (float*)(packed + 16384);     // 4 B
  float* znorm = ssum + 1;                     // 64 KB

  hipMemsetAsync(packed, 0xFF, 16384 * sizeof(unsigned long long), stream);
  hipMemsetAsync(ssum, 0, sizeof(float), stream);

  k_codebook<<<dim3(128, 4), 256, 0, stream>>>(emb, proj, cb, cbT);
  k_norms   <<<32, 256, 0, stream>>>(cbT, norms);
  k_znorm   <<<64, 256, 0, stream>>>(z, znorm);
  k_argmin  <<<dim3(8, 128), 256, 0, stream>>>(z, cbT, norms, znorm, packed);
  k_output  <<<512, 256, 0, stream>>>(z, cb, packed, out, idxf, ssum);
  k_final   <<<1, 1, 0, stream>>>(ssum, scal);

  (void)in_sizes; (void)n_in; (void)out_size; (void)ws_size;
}

// Round 3
// 863.562 us; speedup vs baseline: 1.1499x; 1.1499x over previous
//
#include <hip/hip_runtime.h>
#include <cfloat>

// VQ forward, MI355X. z[16,256,32,32] f32, emb[8192,256] f32, proj[256,256] f32.
// N = 16384 rows, K = 8192 codes, D = 256.
// d_out (floats): out[4194304] | loss | commitment | codebook_loss | idx_as_float[16384]
// d_ws: cbT[256][8192] | cb[8192][256] | norms[8192] | packed_u64[16384] | ssum | znorm[16384]
//
// Correctness-critical: reference rounds d = (||z||^2 + ||e||^2) - 2*dot in fp32,
// quantizing scores to ulp(~256) ~ 1.5e-5; ties resolved by np.argmin first-index.
// We emulate the rounding exactly and tie-break via packed (monof(s)<<32|k) atomicMin.

constexpr int Dd = 256;
constexpr int Kc = 8192;
constexpr float INV_M = 1.0f / 4194304.0f;

#define GLOBAL_AS __attribute__((address_space(1)))
#define LDS_AS    __attribute__((address_space(3)))

__device__ __forceinline__ unsigned monof(float f) {
  unsigned u = __float_as_uint(f);
  return (u & 0x80000000u) ? ~u : (u | 0x80000000u);
}

// ---- K1: codebook = emb @ proj^T, written as cb[k][d] and cbT[d][k] ----
__global__ __launch_bounds__(256)
void k_codebook(const float* __restrict__ emb, const float* __restrict__ proj,
                float* __restrict__ cb, float* __restrict__ cbT) {
  __shared__ float et[64 * 65];
  __shared__ float pt[64 * 65];
  const int t = threadIdx.x;
  const int tx = t & 15, ty = t >> 4;
  const int kb = blockIdx.x * 64;
  const int db = blockIdx.y * 64;
  float acc[4][4];
#pragma unroll
  for (int u = 0; u < 4; ++u)
#pragma unroll
    for (int v = 0; v < 4; ++v) acc[u][v] = 0.f;

  const int jm = t & 15;
  const int q  = t >> 4;

  for (int jc = 0; jc < Dd; jc += 64) {
    __syncthreads();
#pragma unroll
    for (int i = 0; i < 4; ++i) {
      const int row = q + i * 16;
      const float4 e4 = *(const float4*)(emb  + (size_t)(kb + row) * Dd + jc + jm * 4);
      const float4 p4 = *(const float4*)(proj + (size_t)(db + row) * Dd + jc + jm * 4);
      et[(jm*4 + 0) * 65 + row] = e4.x;
      et[(jm*4 + 1) * 65 + row] = e4.y;
      et[(jm*4 + 2) * 65 + row] = e4.z;
      et[(jm*4 + 3) * 65 + row] = e4.w;
      pt[(jm*4 + 0) * 65 + row] = p4.x;
      pt[(jm*4 + 1) * 65 + row] = p4.y;
      pt[(jm*4 + 2) * 65 + row] = p4.z;
      pt[(jm*4 + 3) * 65 + row] = p4.w;
    }
    __syncthreads();
#pragma unroll 16
    for (int j = 0; j < 64; ++j) {
      float a[4], b[4];
#pragma unroll
      for (int u = 0; u < 4; ++u) a[u] = et[j*65 + ty*4 + u];
#pragma unroll
      for (int v = 0; v < 4; ++v) b[v] = pt[j*65 + tx*4 + v];
#pragma unroll
      for (int u = 0; u < 4; ++u)
#pragma unroll
        for (int v = 0; v < 4; ++v) acc[u][v] = fmaf(a[u], b[v], acc[u][v]);
    }
  }
#pragma unroll
  for (int u = 0; u < 4; ++u) {
    const int k = kb + ty*4 + u;
#pragma unroll
    for (int v = 0; v < 4; ++v) {
      const int d = db + tx*4 + v;
      cb [(size_t)k * Dd + d] = acc[u][v];
      cbT[(size_t)d * Kc + k] = acc[u][v];
    }
  }
}

// ---- K1b: per-code squared norms ----
__global__ __launch_bounds__(256)
void k_norms(const float* __restrict__ cbT, float* __restrict__ norms) {
  const int k = blockIdx.x * 256 + threadIdx.x;
  float s = 0.f;
  for (int d = 0; d < Dd; ++d) {
    const float v = cbT[(size_t)d * Kc + k];
    s = fmaf(v, v, s);
  }
  norms[k] = s;
}

// ---- K1c: per-row ||z||^2, computed ONCE so all argmin blocks see identical bits ----
__global__ __launch_bounds__(256)
void k_znorm(const float* __restrict__ z, float* __restrict__ znorm) {
  const int n = blockIdx.x * 256 + threadIdx.x;
  const float* p = z + (size_t)(n >> 10) * 262144 + (n & 1023);
  float s = 0.f;
  for (int d = 0; d < Dd; ++d) {
    const float v = p[(size_t)d * 1024];
    s = fmaf(v, v, s);
  }
  znorm[n] = s;
}

// ---- K2: fused distance + argmin.  256 rows x (8 kt x 128 cols) per block ----
// Per-thread 16 rows x 8 cols. LDS layouts chosen so every ds_read_b128's
// wave-wide address set is 16 contiguous float4s (4-way broadcast) -> each
// 8-lane phase hits each bank exactly once: conflict-free.
// Staging via global_load_lds width=16 (no VGPR round-trip, no ds_writes).
__global__ __launch_bounds__(256, 2)
void k_argmin(const float* __restrict__ z, const float* __restrict__ cbT,
              const float* __restrict__ norms, const float* __restrict__ znorm,
              unsigned long long* __restrict__ packed) {
  __shared__ float zs[32 * 256];   // [j][256 rows]  32 KB
  __shared__ float es[32 * 128];   // [j][128 cols]  16 KB
  const int t    = threadIdx.x;
  const int tx   = t & 15;         // col group
  const int ty   = t >> 4;         // row group (0..15)
  const int lane = t & 63;
  const int wv   = t >> 6;         // wave 0..3
  const int nbase = blockIdx.y * 256;   // 256-aligned => single b, contiguous hw
  const int kbase = blockIdx.x * 1024;
  const float* zb = z + (size_t)(nbase >> 10) * 262144 + (nbase & 1023);

  // per-thread rows: lr = s*64 + ty*4 + rr  (s=0..3, rr=0..3)
  float zn[4][4];
#pragma unroll
  for (int s = 0; s < 4; ++s)
#pragma unroll
    for (int rr = 0; rr < 4; ++rr)
      zn[s][rr] = znorm[nbase + s * 64 + ty * 4 + rr];

  float mv[4][4];
  int   mi[4][4];
#pragma unroll
  for (int s = 0; s < 4; ++s)
#pragma unroll
    for (int rr = 0; rr < 4; ++rr) { mv[s][rr] = FLT_MAX; mi[s][rr] = 0; }

#pragma unroll 1
  for (int kt = 0; kt < 8; ++kt) {
    const int kstart = kbase + kt * 128;
    float acc[4][4][2][4];
#pragma unroll
    for (int s = 0; s < 4; ++s)
#pragma unroll
      for (int rr = 0; rr < 4; ++rr)
#pragma unroll
        for (int h = 0; h < 2; ++h)
#pragma unroll
          for (int cc = 0; cc < 4; ++cc) acc[s][rr][h][cc] = 0.f;

#pragma unroll 1
    for (int dc = 0; dc < Dd; dc += 32) {
      __syncthreads();
      // zs: 32 rows of 1024 B; wave wv stages j = wv*8 .. wv*8+7
#pragma unroll
      for (int i = 0; i < 8; ++i) {
        const int j = wv * 8 + i;
        const float* gp = zb + (size_t)(dc + j) * 1024 + lane * 4;
        __builtin_amdgcn_global_load_lds(
            (const GLOBAL_AS void*)gp,
            (LDS_AS void*)(zs + j * 256), 16, 0, 0);
      }
      // es: 16 KB as 16 wave-instrs of 1024 B; instr q covers j-pair (2q,2q+1)
#pragma unroll
      for (int i = 0; i < 4; ++i) {
        const int q = wv * 4 + i;
        const float* gp = cbT + (size_t)(dc + 2 * q + (lane >> 5)) * Kc
                              + kstart + (lane & 31) * 4;
        __builtin_amdgcn_global_load_lds(
            (const GLOBAL_AS void*)gp,
            (LDS_AS void*)(es + q * 256), 16, 0, 0);
      }
      __syncthreads();

#pragma unroll 2
      for (int j = 0; j < 32; ++j) {
        float4 za[4], ea[2];
#pragma unroll
        for (int s = 0; s < 4; ++s)
          za[s] = *(const float4*)(zs + j * 256 + s * 64 + ty * 4);
#pragma unroll
        for (int h = 0; h < 2; ++h)
          ea[h] = *(const float4*)(es + j * 128 + h * 64 + tx * 4);
        const float zr[4][4] = {{za[0].x,za[0].y,za[0].z,za[0].w},
                                {za[1].x,za[1].y,za[1].z,za[1].w},
                                {za[2].x,za[2].y,za[2].z,za[2].w},
                                {za[3].x,za[3].y,za[3].z,za[3].w}};
        const float er[2][4] = {{ea[0].x,ea[0].y,ea[0].z,ea[0].w},
                                {ea[1].x,ea[1].y,ea[1].z,ea[1].w}};
#pragma unroll
        for (int s = 0; s < 4; ++s)
#pragma unroll
          for (int rr = 0; rr < 4; ++rr)
#pragma unroll
            for (int h = 0; h < 2; ++h)
#pragma unroll
              for (int cc = 0; cc < 4; ++cc)
                acc[s][rr][h][cc] =
                    fmaf(zr[s][rr], er[h][cc], acc[s][rr][h][cc]);
      }
    }
    // Quantized fold: s = fl( fl(znorm + enorm) - 2*acc ).  k ascending within
    // a thread's scan; strict '<' keeps earliest index.
#pragma unroll
    for (int h = 0; h < 2; ++h)
#pragma unroll
      for (int cc = 0; cc < 4; ++cc) {
        const int k = kstart + h * 64 + tx * 4 + cc;
        const float nk = norms[k];
#pragma unroll
        for (int s = 0; s < 4; ++s)
#pragma unroll
          for (int rr = 0; rr < 4; ++rr) {
            const float t1 = zn[s][rr] + nk;
            const float sc = t1 - 2.0f * acc[s][rr][h][cc];
            if (sc < mv[s][rr]) { mv[s][rr] = sc; mi[s][rr] = k; }
          }
      }
  }
  // reduce across the 16 tx lanes of each ty group, then one u64 atomicMin/row
#pragma unroll
  for (int s = 0; s < 4; ++s)
#pragma unroll
    for (int rr = 0; rr < 4; ++rr) {
      unsigned long long p =
          ((unsigned long long)monof(mv[s][rr]) << 32) | (unsigned)mi[s][rr];
#pragma unroll
      for (int m = 1; m < 16; m <<= 1) {
        const unsigned long long o = __shfl_xor(p, m, 64);
        if (o < p) p = o;
      }
      if (tx == 0) atomicMin(&packed[nbase + s * 64 + ty * 4 + rr], p);
    }
}

// ---- K3: gather codes, write out (NCHW), idx floats, reduce SSE ----
__global__ __launch_bounds__(256)
void k_output(const float* __restrict__ z, const float* __restrict__ cb,
              const unsigned long long* __restrict__ packed,
              float* __restrict__ out, float* __restrict__ idxf,
              float* __restrict__ ssum) {
  __shared__ float zqT[256 * 33];
  __shared__ float part[4];
  const int t = threadIdx.x;
  const int blk = blockIdx.x;       // = b*32 + h
  const int nbase = blk * 32;

  {
    const int nl = t >> 3, m = t & 7;
    const int idx = (int)(packed[nbase + nl] & 0xFFFFFFFFull);
    const float* row = cb + (size_t)idx * Dd;
#pragma unroll
    for (int i = 0; i < 8; ++i) {
      const int d0 = m * 4 + i * 32;
      const float4 v = *(const float4*)(row + d0);
      zqT[(d0 + 0) * 33 + nl] = v.x;
      zqT[(d0 + 1) * 33 + nl] = v.y;
      zqT[(d0 + 2) * 33 + nl] = v.z;
      zqT[(d0 + 3) * 33 + nl] = v.w;
    }
    if (t < 32)
      idxf[nbase + t] = (float)(unsigned)(packed[nbase + t] & 0xFFFFFFFFull);
  }
  __syncthreads();

  const int w = t & 31, cg = t >> 5;
  const size_t base = (size_t)(blk >> 5) * 262144 + (size_t)(blk & 31) * 32 + w;
  float local = 0.f;
#pragma unroll
  for (int cc = 0; cc < 32; ++cc) {
    const int c = cg * 32 + cc;
    const float q  = zqT[c * 33 + w];
    const float zv = z[base + (size_t)c * 1024];
    out[base + (size_t)c * 1024] = q;
    const float dd = q - zv;
    local = fmaf(dd, dd, local);
  }
  float v = local;
#pragma unroll
  for (int m = 1; m < 64; m <<= 1) v += __shfl_xor(v, m, 64);
  if ((t & 63) == 0) part[t >> 6] = v;
  __syncthreads();
  if (t == 0) atomicAdd(ssum, part[0] + part[1] + part[2] + part[3]);
}

// ---- K4: finalize scalars ----
__global__ void k_final(const float* __restrict__ ssum, float* __restrict__ scal) {
  const float m = *ssum * INV_M;
  scal[0] = 1.25f * m;   // loss
  scal[1] = 0.25f * m;   // commitment_loss
  scal[2] = m;           // codebook_loss
}

extern "C" void kernel_launch(void* const* d_in, const int* in_sizes, int n_in,
                              void* d_out, int out_size, void* d_ws, size_t ws_size,
                              hipStream_t stream) {
  const float* z    = (const float*)d_in[0];
  const float* emb  = (const float*)d_in[1];
  const float* proj = (const float*)d_in[2];

  float* out  = (float*)d_out;
  float* scal = out + 4194304;
  float* idxf = out + 4194307;

  float* cbT   = (float*)d_ws;                 // 8 MB
  float* cb    = cbT + 2097152;                // 8 MB
  float* norms = cb + 2097152;                 // 32 KB
  unsigned long long* packed =
      (unsigned long long*)(norms + 8192);     // 128 KB
  float* ssum  = (float*)(packed + 16384);     // 4 B
  float* znorm = ssum + 1;                     // 64 KB

  hipMemsetAsync(packed, 0xFF, 16384 * sizeof(unsigned long long), stream);
  hipMemsetAsync(ssum, 0, sizeof(float), stream);

  k_codebook<<<dim3(128, 4), 256, 0, stream>>>(emb, proj, cb, cbT);
  k_norms   <<<32, 256, 0, stream>>>(cbT, norms);
  k_znorm   <<<64, 256, 0, stream>>>(z, znorm);
  k_argmin  <<<dim3(8, 64), 256, 0, stream>>>(z, cbT, norms, znorm, packed);
  k_output  <<<512, 256, 0, stream>>>(z, cb, packed, out, idxf, ssum);
  k_final   <<<1, 1, 0, stream>>>(ssum, scal);

  (void)in_sizes; (void)n_in; (void)out_size; (void)ws_size;
}